// Round 6
// baseline (116.749 us; speedup 1.0000x reference)
//
#include <hip/hip_runtime.h>
#include <hip/hip_bf16.h>

typedef __bf16 bf16x8 __attribute__((ext_vector_type(8)));
typedef float f32x4 __attribute__((ext_vector_type(4)));
typedef unsigned short u16;

#define H_SZ 768
#define NH 12
#define SEQ 1024

// fp32 -> bf16 round-to-nearest-even
__device__ __forceinline__ u16 f2b(float f) {
  unsigned u = __builtin_bit_cast(unsigned, f);
  unsigned r = (u + 0x7FFFu + ((u >> 16) & 1u)) >> 16;
  return (u16)r;
}

#define GLL16(g, l)                                                            \
  __builtin_amdgcn_global_load_lds(                                            \
      (const __attribute__((address_space(1))) void*)(g),                      \
      (__attribute__((address_space(3))) void*)(l), 16, 0, 0)

// ---------------- memory plan ----------------
// d_out (6291456 B, fp32 2048x768, fully overwritten by final GEMM):
//   xb : bf16 X      [0, 3145728)        live: prep -> QKV GEMM
//   qw : bf16 Q plan [3145728, 6291456)  live: QKV GEMM -> attn
// d_ws (10.5 MiB used):
//   wqkvb : 2304x768 bf16 @ 0        (3538944)  live: prep -> QKV GEMM
//   kw    : 24x1024x64   @ 3538944  (3145728)  live: QKV GEMM -> attn
//   vw    : 24x1024x64   @ 6684672  (3145728)  live: QKV GEMM -> attn
//   wob   : 768x768 bf16 @ 9830400  (1179648)  live: prep -> out GEMM
//   ctx   : 2048x768bf16 @ 0 (alias wqkvb)     live: attn -> out GEMM
#define WQKV_OFF 0u
#define KW_OFF 3538944u
#define VW_OFF 6684672u
#define WO_OFF 9830400u
#define CTX_OFF 0u
#define XB_OUT_OFF 0u
#define QW_OUT_OFF 3145728u

// TUNING LOG (MI355X, total dur_us incl ~105us fixed harness fill/restore):
//   R2 m97-style 2-barrier GEMMs ............ 134.1
//   R3 + single-barrier dbuf GLL ............ 129.7  WIN
//   R4 B-frags direct-from-global ........... 140.6  REGRESS — don't revisit
//   R5 revert R4 + out-proj TM=64 (192 blk) . 126.65 WIN (filled idle CUs)
//   R6 QKV TN=192 (192 fat blocks) .......... 130.4  REGRESS (idle CUs)
//   R7 QKV TM=64 (576 thin blocks) .......... 125.70 ~NEUTRAL
//   R8 BK=64 + XOR-swizzled staging/reads ... 118.31 BIG WIN (-7.4): 8-way
//      bank conflict on fragment ds_read_b128 was the dominant GEMM cost.
//   R9 3-buffer counted-vmcnt pipeline ...... 126.22 REGRESS (+7.9): T4
//      needs a phase-interleaved schedule; LDS 72KB cut blocks/CU. Do not
//      revisit without a full 8-phase restructure.
//   R10 QKV 128x128 fat tile ................ 120.75 REGRESS (+2.4): loop
//      is latency-bound; 576-block co-residency was hiding barrier drain.
//      LESSON: every co-residency-reducing change (R6/R9/R10) regressed.
//   R11 out-proj 64x64 (384 blk) ............ 115.82 WIN (-2.5): out-proj
//      had 64 idle CUs + zero co-residency. Same mechanism as R5/R7.
//   R12 (this) XCD-aware block swizzle (T1) on both GEMMs + attn:
//      default round-robin dispatch scatters blocks -> per-XCD working set
//      (QKV: 6.6MB) > 4MB L2 -> staging misses to L3. Contiguous 72-block
//      chunks per XCD fit (3.9MB QKV / 1.6MB out-proj / 1.15MB attn) ->
//      GLL16 latency drops, which co-residency then fully covers. All
//      grids divisible by 8 (576/384/384) -> simple bijective form.

// ---------------- pass 1: fp32 -> bf16 conversions ----------------
__global__ __launch_bounds__(256) void prep_kernel(
    const float* __restrict__ hs, const float* __restrict__ wq,
    const float* __restrict__ wk, const float* __restrict__ wv,
    const float* __restrict__ wo, u16* __restrict__ xb,
    u16* __restrict__ wqkvb, u16* __restrict__ wob) {
  int c = blockIdx.x * 256 + threadIdx.x;  // one float4 chunk
  const float* src;
  u16* dst;
  if (c < 393216) {                       // hidden 2048*768/4
    src = hs + (size_t)c * 4; dst = xb + (size_t)c * 4;
  } else if (c < 540672) {                // Wq 768*768/4
    int i = c - 393216; src = wq + (size_t)i * 4; dst = wqkvb + (size_t)i * 4;
  } else if (c < 688128) {                // Wk
    int i = c - 540672; src = wk + (size_t)i * 4; dst = wqkvb + 589824 + (size_t)i * 4;
  } else if (c < 835584) {                // Wv
    int i = c - 688128; src = wv + (size_t)i * 4; dst = wqkvb + 1179648 + (size_t)i * 4;
  } else {                                // Wo
    int i = c - 835584; src = wo + (size_t)i * 4; dst = wob + (size_t)i * 4;
  }
  float4 v = *(const float4*)src;
  ushort4 o;
  o.x = f2b(v.x); o.y = f2b(v.y); o.z = f2b(v.z); o.w = f2b(v.w);
  *(ushort4*)dst = o;
}

// ---------------- double-buffered bf16 GEMM, C = A * B^T ----------------
// Both operands staged via global_load_lds into LDS, single barrier per
// K-iter, prefetch into the alternate buffer in flight across the compute
// phase. Staging is XOR-swizzled: LDS dest is linear (GLL16 requires it);
// the global source 16B-chunk column is XOR'd with (row & CMASK) so that
// fragment reads (same XOR applied) are bank-conflict-free.
// Block-index is XCD-swizzled (T1): XCD k gets NWG/8 CONTIGUOUS tiles so
// its private L2 holds a small contiguous slice of A + the shared B panel.
// MODE 0: QKV epilogue -> scatter bf16 into q/k/v [plane][s][64] + bias
// MODE 1: out-proj epilogue -> fp32 out[m][n] + bias
template <int MODE, int TM, int TN, int BK, int GX, int NWG>
__global__ __launch_bounds__(256) void gemm_bt(
    const u16* __restrict__ A, const u16* __restrict__ Bm, int K,
    const float* __restrict__ b0, const float* __restrict__ b1,
    const float* __restrict__ b2, u16* __restrict__ oq, u16* __restrict__ ok,
    u16* __restrict__ ov, float* __restrict__ of) {
  constexpr int MI = TM / 32;        // 16-row i-tiles per wave (2 waves in M)
  constexpr int NJ = TN / 32;        // 16-col j-tiles per wave (2 waves in N)
  constexpr int KS = BK / 32;        // 32-wide k-steps per K-iter
  constexpr int CPR = BK / 8;        // 16B chunks per row
  constexpr int CMASK = CPR - 1;
  constexpr int CHA = TM * CPR / 256;  // A staging chunks per thread
  constexpr int CHB = TN * CPR / 256;  // B staging chunks per thread
  __shared__ u16 As[2][TM * BK];
  __shared__ u16 Bs[2][TN * BK];
  const int tid = threadIdx.x;
  const int lane = tid & 63;
  const int wave = tid >> 6;
  const int wm = (wave & 1) * (TM / 2), wn = (wave >> 1) * (TN / 2);
  const int lrow = lane & 15, quad = lane >> 4;

  // T1 XCD swizzle (NWG % 8 == 0 -> bijective): XCD = bid & 7 under
  // round-robin dispatch; give it a contiguous chunk of tile space.
  const int bid = blockIdx.y * GX + blockIdx.x;
  const int swz = (bid & 7) * (NWG / 8) + (bid >> 3);
  const int bx = swz % GX, by = swz / GX;

  const u16* Ab = A + (size_t)by * TM * K;
  const u16* Bb = Bm + (size_t)bx * TN * K;

  // staging chunk plan: thread t covers linear chunks t, t+256, ...
  // linear chunk bi -> LDS row bi/CPR, LDS col-chunk bi%CPR; the GLOBAL
  // col-chunk it fetches is (bi%CPR) ^ (row & CMASK)  [u16 offset *8]
  int ar[CHA], ac[CHA];
#pragma unroll
  for (int c = 0; c < CHA; c++) {
    int bi = tid + c * 256;
    ar[c] = bi / CPR;
    ac[c] = ((bi & CMASK) ^ (ar[c] & CMASK)) * 8;
  }
  int br[CHB], bc[CHB];
#pragma unroll
  for (int c = 0; c < CHB; c++) {
    int bi = tid + c * 256;
    br[c] = bi / CPR;
    bc[c] = ((bi & CMASK) ^ (br[c] & CMASK)) * 8;
  }

  f32x4 acc[MI][NJ] = {};

  // prologue: loads for kt=0 into buffer 0
#pragma unroll
  for (int c = 0; c < CHA; c++)
    GLL16(Ab + (size_t)ar[c] * K + ac[c], &As[0][(tid + c * 256) * 8]);
#pragma unroll
  for (int c = 0; c < CHB; c++)
    GLL16(Bb + (size_t)br[c] * K + bc[c], &Bs[0][(tid + c * 256) * 8]);

  int cur = 0;
  for (int kt = 0; kt < K; kt += BK) {
    __syncthreads();  // drains vmcnt: buf[cur] ready; prior reads of buf[cur^1] done
    const int nxt = cur ^ 1;
    if (kt + BK < K) {  // prefetch next tile into alternate buffer (in flight
                        // across this iteration's compute)
#pragma unroll
      for (int c = 0; c < CHA; c++)
        GLL16(Ab + (size_t)ar[c] * K + kt + BK + ac[c],
              &As[nxt][(tid + c * 256) * 8]);
#pragma unroll
      for (int c = 0; c < CHB; c++)
        GLL16(Bb + (size_t)br[c] * K + kt + BK + bc[c],
              &Bs[nxt][(tid + c * 256) * 8]);
    }
#pragma unroll
    for (int ks = 0; ks < KS; ks++) {
      bf16x8 af[MI], bf[NJ];
#pragma unroll
      for (int i = 0; i < MI; i++) {
        int row = wm + i * 16 + lrow;
        int lc = (ks * 4 + quad) ^ (row & CMASK);
        af[i] = *(const bf16x8*)&As[cur][row * BK + lc * 8];
      }
#pragma unroll
      for (int j = 0; j < NJ; j++) {
        int row = wn + j * 16 + lrow;
        int lc = (ks * 4 + quad) ^ (row & CMASK);
        bf[j] = *(const bf16x8*)&Bs[cur][row * BK + lc * 8];
      }
#pragma unroll
      for (int i = 0; i < MI; i++)
#pragma unroll
        for (int j = 0; j < NJ; j++)
          acc[i][j] = __builtin_amdgcn_mfma_f32_16x16x32_bf16(
              af[i], bf[j], acc[i][j], 0, 0, 0);
    }
    cur = nxt;
  }

  // C/D layout (m89-verified): col = lane&15, row = quad*4 + reg
  if (MODE == 0) {
#pragma unroll
    for (int j = 0; j < NJ; j++) {
      int nbase = bx * TN + wn + j * 16;  // 16-col group never straddles 768-boundary
      int sec = (nbase >= 1536) ? 2 : (nbase >= 768 ? 1 : 0);
      int nn = nbase - sec * 768 + lrow;
      const float* bp = (sec == 0) ? b0 : (sec == 1 ? b1 : b2);
      u16* dst = (sec == 0) ? oq : (sec == 1 ? ok : ov);
      float bias = bp[nn];
      int h = nn >> 6, d = nn & 63;
#pragma unroll
      for (int i = 0; i < MI; i++) {
        int mbase = by * TM + wm + i * 16 + quad * 4;
#pragma unroll
        for (int r = 0; r < 4; r++) {
          int mm = mbase + r;
          int plane = (mm >> 10) * NH + h;  // b*12 + h
          dst[((size_t)(plane << 10) + (mm & 1023)) * 64 + d] =
              f2b(acc[i][j][r] + bias);
        }
      }
    }
  } else {
#pragma unroll
    for (int j = 0; j < NJ; j++) {
      int n = bx * TN + wn + j * 16 + lrow;
      float bias = b0[n];
#pragma unroll
      for (int i = 0; i < MI; i++) {
        int mbase = by * TM + wm + i * 16 + quad * 4;
#pragma unroll
        for (int r = 0; r < 4; r++) {
          int mm = mbase + r;
          of[(size_t)mm * H_SZ + n] = acc[i][j][r] + bias;
        }
      }
    }
  }
}

// ---------------- pass 3: sliding-window attention ----------------
// One block per (plane = b*12+h, 64-query tile). Window of each query tile
// is fully inside a 128-key tile [s0-32, s0+96) -> single-pass softmax.
// Reference semantics: keys/values ZERO-padded (not masked): positions in
// window but outside [0,S) contribute score=0 to softmax and value=0.
// Block-index is XCD-swizzled plane-contiguous: each XCD gets 48 contiguous
// (bh,qb) pairs = 3 full planes of K/V/Q (~1.15MB) resident in its L2.
__global__ __launch_bounds__(256) void attn_kernel(
    const u16* __restrict__ qw, const u16* __restrict__ kw,
    const u16* __restrict__ vw, u16* __restrict__ ctx) {
  __shared__ u16 VT[64][136];      // V^T: [d][window key], pad 136 (2-way=free)
  __shared__ u16 P[4][16][136];    // per-wave P tile (C-layout -> A-layout)
  const int tid = threadIdx.x;
  const int lane = tid & 63;
  const int wave = tid >> 6;
  const int lrow = lane & 15, quad = lane >> 4;
  // T1 swizzle over 384 = 8 XCDs x 48; plane-major in swizzled space.
  const int bid = blockIdx.y * 24 + blockIdx.x;
  const int swz = (bid & 7) * 48 + (bid >> 3);
  const int bh = swz >> 4;     // 0..23
  const int qb = swz & 15;     // 0..15
  const int s0 = qb * 64;
  const int b = bh / NH, h = bh - b * NH;

  const u16* qp = qw + (size_t)bh * SEQ * 64;
  const u16* kp = kw + (size_t)bh * SEQ * 64;
  const u16* vp = vw + (size_t)bh * SEQ * 64;

  // Issue ALL Q/K global loads first: their latency hides behind V staging +
  // the barrier below.
  const u16* qbase = qp + (size_t)(s0 + wave * 16 + lrow) * 64 + quad * 8;
  bf16x8 aq0 = *(const bf16x8*)qbase;
  bf16x8 aq1 = *(const bf16x8*)(qbase + 32);
  bf16x8 bk0[8], bk1[8];
#pragma unroll
  for (int nt = 0; nt < 8; nt++) {
    int key = s0 - 32 + nt * 16 + lrow;
    int kc = min(max(key, 0), SEQ - 1);  // clamp: content masked by index below
    const u16* kb = kp + (size_t)kc * 64 + quad * 8;
    bk0[nt] = *(const bf16x8*)kb;
    bk1[nt] = *(const bf16x8*)(kb + 32);
  }

  // stage V^T with zeros for out-of-range keys
#pragma unroll
  for (int it = 0; it < 4; it++) {
    int chunk = it * 256 + tid;   // 0..1023
    int r = chunk & 127;          // window row (key = s0-32+r)
    int c8 = chunk >> 7;          // d block
    int key = s0 - 32 + r;
    uint4 val = make_uint4(0, 0, 0, 0);
    if (key >= 0 && key < SEQ)
      val = *(const uint4*)(vp + (size_t)key * 64 + c8 * 8);
    union { uint4 u; u16 s[8]; } uu;
    uu.u = val;
#pragma unroll
    for (int t = 0; t < 8; t++) VT[c8 * 8 + t][r] = uu.s[t];
  }
  __syncthreads();

  // S = Q K^T over 128-key tile (8 n-tiles x 2 k-steps)
  f32x4 sc[8];
#pragma unroll
  for (int nt = 0; nt < 8; nt++) {
    f32x4 c = {0.f, 0.f, 0.f, 0.f};
    c = __builtin_amdgcn_mfma_f32_16x16x32_bf16(aq0, bk0[nt], c, 0, 0, 0);
    c = __builtin_amdgcn_mfma_f32_16x16x32_bf16(aq1, bk1[nt], c, 0, 0, 0);
    sc[nt] = c;
  }

  // 3-way mask: outside window -> -inf; zero-padded key -> score 0; else scale
#pragma unroll
  for (int nt = 0; nt < 8; nt++) {
#pragma unroll
    for (int r = 0; r < 4; r++) {
      int j = s0 - 32 + nt * 16 + lrow;        // key (col)
      int i = s0 + wave * 16 + quad * 4 + r;   // query (row)
      int w = j - i + 32;
      float s = sc[nt][r] * 0.125f;
      if (w < 0 || w > 63) s = -1e30f;
      else if (j < 0 || j >= SEQ) s = 0.0f;
      sc[nt][r] = s;
    }
  }

  // row softmax: in-register across 8 n-tiles, then 16-lane xor-reduce
  float linv[4];
#pragma unroll
  for (int r = 0; r < 4; r++) {
    float m = sc[0][r];
#pragma unroll
    for (int nt = 1; nt < 8; nt++) m = fmaxf(m, sc[nt][r]);
    m = fmaxf(m, __shfl_xor(m, 1, 64));
    m = fmaxf(m, __shfl_xor(m, 2, 64));
    m = fmaxf(m, __shfl_xor(m, 4, 64));
    m = fmaxf(m, __shfl_xor(m, 8, 64));
    float l = 0.f;
#pragma unroll
    for (int nt = 0; nt < 8; nt++) {
      float p = __expf(sc[nt][r] - m);
      sc[nt][r] = p;
      l += p;
    }
    l += __shfl_xor(l, 1, 64);
    l += __shfl_xor(l, 2, 64);
    l += __shfl_xor(l, 4, 64);
    l += __shfl_xor(l, 8, 64);
    linv[r] = 1.0f / l;  // never 0: diagonal key always contributes
  }

  // P (C-layout) -> LDS bf16 in row-major for A-operand reads (wave-private)
#pragma unroll
  for (int nt = 0; nt < 8; nt++)
#pragma unroll
    for (int r = 0; r < 4; r++)
      P[wave][quad * 4 + r][nt * 16 + lrow] = f2b(sc[nt][r]);

  // ctx = P~ * V  (A from P LDS, B from VT LDS), then normalize by 1/l
#pragma unroll
  for (int dt = 0; dt < 4; dt++) {
    f32x4 o = {0.f, 0.f, 0.f, 0.f};
#pragma unroll
    for (int kk = 0; kk < 4; kk++) {
      bf16x8 pa = *(const bf16x8*)&P[wave][lrow][kk * 32 + quad * 8];
      bf16x8 vb = *(const bf16x8*)&VT[dt * 16 + lrow][kk * 32 + quad * 8];
      o = __builtin_amdgcn_mfma_f32_16x16x32_bf16(pa, vb, o, 0, 0, 0);
    }
#pragma unroll
    for (int r = 0; r < 4; r++) {
      int token = b * SEQ + s0 + wave * 16 + quad * 4 + r;
      ctx[(size_t)token * H_SZ + h * 64 + dt * 16 + lrow] =
          f2b(o[r] * linv[r]);
    }
  }
}

extern "C" void kernel_launch(void* const* d_in, const int* in_sizes, int n_in,
                              void* d_out, int out_size, void* d_ws,
                              size_t ws_size, hipStream_t stream) {
  (void)in_sizes; (void)n_in; (void)out_size; (void)ws_size;
  const float* hs = (const float*)d_in[0];
  const float* Wq = (const float*)d_in[1];
  const float* bq = (const float*)d_in[2];
  const float* Wk = (const float*)d_in[3];
  const float* bk = (const float*)d_in[4];
  const float* Wv = (const float*)d_in[5];
  const float* bv = (const float*)d_in[6];
  const float* Wo = (const float*)d_in[7];
  const float* bo = (const float*)d_in[8];
  float* out = (float*)d_out;
  char* ws = (char*)d_ws;
  char* ob = (char*)d_out;
  // d_out-resident scratch (fully overwritten by final GEMM):
  u16* xb = (u16*)(ob + XB_OUT_OFF);  // bf16 X, dead after QKV GEMM
  u16* qw = (u16*)(ob + QW_OUT_OFF);  // Q planes, dead after attn
  // ws-resident scratch (10.5 MiB total):
  u16* wqkvb = (u16*)(ws + WQKV_OFF);
  u16* kw = (u16*)(ws + KW_OFF);
  u16* vw = (u16*)(ws + VW_OFF);
  u16* wob = (u16*)(ws + WO_OFF);
  u16* ctx = (u16*)(ws + CTX_OFF);  // aliases wqkvb (dead after QKV GEMM)

  prep_kernel<<<3840, 256, 0, stream>>>(hs, Wq, Wk, Wv, Wo, xb, wqkvb, wob);
  gemm_bt<0, 64, 128, 64, 18, 576><<<dim3(18, 32), 256, 0, stream>>>(
      xb, wqkvb, 768, bq, bk, bv, qw, kw, vw, nullptr);
  attn_kernel<<<dim3(24, 16), 256, 0, stream>>>(qw, kw, vw, ctx);
  gemm_bt<1, 64, 64, 64, 12, 384><<<dim3(12, 32), 256, 0, stream>>>(
      ctx, wob, 768, bo, nullptr, nullptr, nullptr, nullptr, nullptr, out);
}

// Round 7
// 115.415 us; speedup vs baseline: 1.0116x; 1.0116x over previous
//
#include <hip/hip_runtime.h>
#include <hip/hip_bf16.h>

typedef __bf16 bf16x8 __attribute__((ext_vector_type(8)));
typedef float f32x4 __attribute__((ext_vector_type(4)));
typedef unsigned short u16;

#define H_SZ 768
#define NH 12
#define SEQ 1024

// fp32 -> bf16 round-to-nearest-even
__device__ __forceinline__ u16 f2b(float f) {
  unsigned u = __builtin_bit_cast(unsigned, f);
  unsigned r = (u + 0x7FFFu + ((u >> 16) & 1u)) >> 16;
  return (u16)r;
}

#define GLL16(g, l)                                                            \
  __builtin_amdgcn_global_load_lds(                                            \
      (const __attribute__((address_space(1))) void*)(g),                      \
      (__attribute__((address_space(3))) void*)(l), 16, 0, 0)

// ---------------- memory plan ----------------
// d_out (6291456 B, fp32 2048x768, fully overwritten by final GEMM):
//   xb : bf16 X      [0, 3145728)        live: prep -> QKV GEMM
//   qw : bf16 Q plan [3145728, 6291456)  live: QKV GEMM -> attn
// d_ws (10.5 MiB used):
//   wqkvb : 2304x768 bf16 @ 0        (3538944)  live: prep -> QKV GEMM
//   kw    : 24x1024x64   @ 3538944  (3145728)  live: QKV GEMM -> attn
//   vw    : 24x1024x64   @ 6684672  (3145728)  live: QKV GEMM -> attn
//   wob   : 768x768 bf16 @ 9830400  (1179648)  live: prep -> out GEMM
//   ctx   : 2048x768bf16 @ 0 (alias wqkvb)     live: attn -> out GEMM
#define WQKV_OFF 0u
#define KW_OFF 3538944u
#define VW_OFF 6684672u
#define WO_OFF 9830400u
#define CTX_OFF 0u
#define XB_OUT_OFF 0u
#define QW_OUT_OFF 3145728u

// TUNING LOG (MI355X, total dur_us incl ~105us fixed harness fill/restore):
//   R2 m97-style 2-barrier GEMMs ............ 134.1
//   R3 + single-barrier dbuf GLL ............ 129.7  WIN
//   R4 B-frags direct-from-global ........... 140.6  REGRESS — don't revisit
//   R5 revert R4 + out-proj TM=64 (192 blk) . 126.65 WIN (filled idle CUs)
//   R6 QKV TN=192 (192 fat blocks) .......... 130.4  REGRESS (idle CUs)
//   R7 QKV TM=64 (576 thin blocks) .......... 125.70 ~NEUTRAL
//   R8 BK=64 + XOR-swizzled staging/reads ... 118.31 BIG WIN (-7.4): 8-way
//      bank conflict on fragment ds_read_b128 was the dominant GEMM cost.
//   R9 3-buffer counted-vmcnt pipeline ...... 126.22 REGRESS (+7.9): T4
//      needs a phase-interleaved schedule; LDS 72KB cut blocks/CU. Do not
//      revisit without a full 8-phase restructure.
//   R10 QKV 128x128 fat tile ................ 120.75 REGRESS (+2.4): loop
//      is latency-bound; 576-block co-residency was hiding barrier drain.
//      LESSON: every co-residency-reducing change (R6/R9/R10) regressed.
//   R11 out-proj 64x64 (384 blk) ............ 115.82 WIN (-2.5): out-proj
//      had 64 idle CUs + zero co-residency. Same mechanism as R5/R7.
//   R12 XCD-aware block swizzle (T1) ........ 116.75 REGRESS (+0.9): all
//      operands L3-fit -> swizzle costs ~2% (m160 regime). Reverted.
//   R13 (this) = R11 exactly. Catalog exhausted for this regime: T2 applied,
//      T4/8-phase inapplicable (72-block grid), T1 negative (L3-fit),
//      tile/occupancy space mapped. R11 is the structure's floor.

// ---------------- pass 1: fp32 -> bf16 conversions ----------------
__global__ __launch_bounds__(256) void prep_kernel(
    const float* __restrict__ hs, const float* __restrict__ wq,
    const float* __restrict__ wk, const float* __restrict__ wv,
    const float* __restrict__ wo, u16* __restrict__ xb,
    u16* __restrict__ wqkvb, u16* __restrict__ wob) {
  int c = blockIdx.x * 256 + threadIdx.x;  // one float4 chunk
  const float* src;
  u16* dst;
  if (c < 393216) {                       // hidden 2048*768/4
    src = hs + (size_t)c * 4; dst = xb + (size_t)c * 4;
  } else if (c < 540672) {                // Wq 768*768/4
    int i = c - 393216; src = wq + (size_t)i * 4; dst = wqkvb + (size_t)i * 4;
  } else if (c < 688128) {                // Wk
    int i = c - 540672; src = wk + (size_t)i * 4; dst = wqkvb + 589824 + (size_t)i * 4;
  } else if (c < 835584) {                // Wv
    int i = c - 688128; src = wv + (size_t)i * 4; dst = wqkvb + 1179648 + (size_t)i * 4;
  } else {                                // Wo
    int i = c - 835584; src = wo + (size_t)i * 4; dst = wob + (size_t)i * 4;
  }
  float4 v = *(const float4*)src;
  ushort4 o;
  o.x = f2b(v.x); o.y = f2b(v.y); o.z = f2b(v.z); o.w = f2b(v.w);
  *(ushort4*)dst = o;
}

// ---------------- double-buffered bf16 GEMM, C = A * B^T ----------------
// Both operands staged via global_load_lds into LDS, single barrier per
// K-iter, prefetch into the alternate buffer in flight across the compute
// phase. Staging is XOR-swizzled: LDS dest is linear (GLL16 requires it);
// the global source 16B-chunk column is XOR'd with (row & CMASK) so that
// fragment reads (same XOR applied) are bank-conflict-free.
// MODE 0: QKV epilogue -> scatter bf16 into q/k/v [plane][s][64] + bias
// MODE 1: out-proj epilogue -> fp32 out[m][n] + bias
template <int MODE, int TM, int TN, int BK>
__global__ __launch_bounds__(256) void gemm_bt(
    const u16* __restrict__ A, const u16* __restrict__ Bm, int K,
    const float* __restrict__ b0, const float* __restrict__ b1,
    const float* __restrict__ b2, u16* __restrict__ oq, u16* __restrict__ ok,
    u16* __restrict__ ov, float* __restrict__ of) {
  constexpr int MI = TM / 32;        // 16-row i-tiles per wave (2 waves in M)
  constexpr int NJ = TN / 32;        // 16-col j-tiles per wave (2 waves in N)
  constexpr int KS = BK / 32;        // 32-wide k-steps per K-iter
  constexpr int CPR = BK / 8;        // 16B chunks per row
  constexpr int CMASK = CPR - 1;
  constexpr int CHA = TM * CPR / 256;  // A staging chunks per thread
  constexpr int CHB = TN * CPR / 256;  // B staging chunks per thread
  __shared__ u16 As[2][TM * BK];
  __shared__ u16 Bs[2][TN * BK];
  const int tid = threadIdx.x;
  const int lane = tid & 63;
  const int wave = tid >> 6;
  const int wm = (wave & 1) * (TM / 2), wn = (wave >> 1) * (TN / 2);
  const int lrow = lane & 15, quad = lane >> 4;

  const u16* Ab = A + (size_t)blockIdx.y * TM * K;
  const u16* Bb = Bm + (size_t)blockIdx.x * TN * K;

  // staging chunk plan: thread t covers linear chunks t, t+256, ...
  // linear chunk bi -> LDS row bi/CPR, LDS col-chunk bi%CPR; the GLOBAL
  // col-chunk it fetches is (bi%CPR) ^ (row & CMASK)  [u16 offset *8]
  int ar[CHA], ac[CHA];
#pragma unroll
  for (int c = 0; c < CHA; c++) {
    int bi = tid + c * 256;
    ar[c] = bi / CPR;
    ac[c] = ((bi & CMASK) ^ (ar[c] & CMASK)) * 8;
  }
  int br[CHB], bc[CHB];
#pragma unroll
  for (int c = 0; c < CHB; c++) {
    int bi = tid + c * 256;
    br[c] = bi / CPR;
    bc[c] = ((bi & CMASK) ^ (br[c] & CMASK)) * 8;
  }

  f32x4 acc[MI][NJ] = {};

  // prologue: loads for kt=0 into buffer 0
#pragma unroll
  for (int c = 0; c < CHA; c++)
    GLL16(Ab + (size_t)ar[c] * K + ac[c], &As[0][(tid + c * 256) * 8]);
#pragma unroll
  for (int c = 0; c < CHB; c++)
    GLL16(Bb + (size_t)br[c] * K + bc[c], &Bs[0][(tid + c * 256) * 8]);

  int cur = 0;
  for (int kt = 0; kt < K; kt += BK) {
    __syncthreads();  // drains vmcnt: buf[cur] ready; prior reads of buf[cur^1] done
    const int nxt = cur ^ 1;
    if (kt + BK < K) {  // prefetch next tile into alternate buffer (in flight
                        // across this iteration's compute)
#pragma unroll
      for (int c = 0; c < CHA; c++)
        GLL16(Ab + (size_t)ar[c] * K + kt + BK + ac[c],
              &As[nxt][(tid + c * 256) * 8]);
#pragma unroll
      for (int c = 0; c < CHB; c++)
        GLL16(Bb + (size_t)br[c] * K + kt + BK + bc[c],
              &Bs[nxt][(tid + c * 256) * 8]);
    }
#pragma unroll
    for (int ks = 0; ks < KS; ks++) {
      bf16x8 af[MI], bf[NJ];
#pragma unroll
      for (int i = 0; i < MI; i++) {
        int row = wm + i * 16 + lrow;
        int lc = (ks * 4 + quad) ^ (row & CMASK);
        af[i] = *(const bf16x8*)&As[cur][row * BK + lc * 8];
      }
#pragma unroll
      for (int j = 0; j < NJ; j++) {
        int row = wn + j * 16 + lrow;
        int lc = (ks * 4 + quad) ^ (row & CMASK);
        bf[j] = *(const bf16x8*)&Bs[cur][row * BK + lc * 8];
      }
#pragma unroll
      for (int i = 0; i < MI; i++)
#pragma unroll
        for (int j = 0; j < NJ; j++)
          acc[i][j] = __builtin_amdgcn_mfma_f32_16x16x32_bf16(
              af[i], bf[j], acc[i][j], 0, 0, 0);
    }
    cur = nxt;
  }

  // C/D layout (m89-verified): col = lane&15, row = quad*4 + reg
  if (MODE == 0) {
#pragma unroll
    for (int j = 0; j < NJ; j++) {
      int nbase = blockIdx.x * TN + wn + j * 16;  // 16-col group never straddles 768-boundary
      int sec = (nbase >= 1536) ? 2 : (nbase >= 768 ? 1 : 0);
      int nn = nbase - sec * 768 + lrow;
      const float* bp = (sec == 0) ? b0 : (sec == 1 ? b1 : b2);
      u16* dst = (sec == 0) ? oq : (sec == 1 ? ok : ov);
      float bias = bp[nn];
      int h = nn >> 6, d = nn & 63;
#pragma unroll
      for (int i = 0; i < MI; i++) {
        int mbase = blockIdx.y * TM + wm + i * 16 + quad * 4;
#pragma unroll
        for (int r = 0; r < 4; r++) {
          int mm = mbase + r;
          int plane = (mm >> 10) * NH + h;  // b*12 + h
          dst[((size_t)(plane << 10) + (mm & 1023)) * 64 + d] =
              f2b(acc[i][j][r] + bias);
        }
      }
    }
  } else {
#pragma unroll
    for (int j = 0; j < NJ; j++) {
      int n = blockIdx.x * TN + wn + j * 16 + lrow;
      float bias = b0[n];
#pragma unroll
      for (int i = 0; i < MI; i++) {
        int mbase = blockIdx.y * TM + wm + i * 16 + quad * 4;
#pragma unroll
        for (int r = 0; r < 4; r++) {
          int mm = mbase + r;
          of[(size_t)mm * H_SZ + n] = acc[i][j][r] + bias;
        }
      }
    }
  }
}

// ---------------- pass 3: sliding-window attention ----------------
// One block per (plane = b*12+h, 64-query tile). Window of each query tile
// is fully inside a 128-key tile [s0-32, s0+96) -> single-pass softmax.
// Reference semantics: keys/values ZERO-padded (not masked): positions in
// window but outside [0,S) contribute score=0 to softmax and value=0.
__global__ __launch_bounds__(256) void attn_kernel(
    const u16* __restrict__ qw, const u16* __restrict__ kw,
    const u16* __restrict__ vw, u16* __restrict__ ctx) {
  __shared__ u16 VT[64][136];      // V^T: [d][window key], pad 136 (2-way=free)
  __shared__ u16 P[4][16][136];    // per-wave P tile (C-layout -> A-layout)
  const int tid = threadIdx.x;
  const int lane = tid & 63;
  const int wave = tid >> 6;
  const int lrow = lane & 15, quad = lane >> 4;
  const int bh = blockIdx.x;   // 0..23
  const int qb = blockIdx.y;   // 0..15
  const int s0 = qb * 64;
  const int b = bh / NH, h = bh - b * NH;

  const u16* qp = qw + (size_t)bh * SEQ * 64;
  const u16* kp = kw + (size_t)bh * SEQ * 64;
  const u16* vp = vw + (size_t)bh * SEQ * 64;

  // Issue ALL Q/K global loads first: their latency hides behind V staging +
  // the barrier below.
  const u16* qbase = qp + (size_t)(s0 + wave * 16 + lrow) * 64 + quad * 8;
  bf16x8 aq0 = *(const bf16x8*)qbase;
  bf16x8 aq1 = *(const bf16x8*)(qbase + 32);
  bf16x8 bk0[8], bk1[8];
#pragma unroll
  for (int nt = 0; nt < 8; nt++) {
    int key = s0 - 32 + nt * 16 + lrow;
    int kc = min(max(key, 0), SEQ - 1);  // clamp: content masked by index below
    const u16* kb = kp + (size_t)kc * 64 + quad * 8;
    bk0[nt] = *(const bf16x8*)kb;
    bk1[nt] = *(const bf16x8*)(kb + 32);
  }

  // stage V^T with zeros for out-of-range keys
#pragma unroll
  for (int it = 0; it < 4; it++) {
    int chunk = it * 256 + tid;   // 0..1023
    int r = chunk & 127;          // window row (key = s0-32+r)
    int c8 = chunk >> 7;          // d block
    int key = s0 - 32 + r;
    uint4 val = make_uint4(0, 0, 0, 0);
    if (key >= 0 && key < SEQ)
      val = *(const uint4*)(vp + (size_t)key * 64 + c8 * 8);
    union { uint4 u; u16 s[8]; } uu;
    uu.u = val;
#pragma unroll
    for (int t = 0; t < 8; t++) VT[c8 * 8 + t][r] = uu.s[t];
  }
  __syncthreads();

  // S = Q K^T over 128-key tile (8 n-tiles x 2 k-steps)
  f32x4 sc[8];
#pragma unroll
  for (int nt = 0; nt < 8; nt++) {
    f32x4 c = {0.f, 0.f, 0.f, 0.f};
    c = __builtin_amdgcn_mfma_f32_16x16x32_bf16(aq0, bk0[nt], c, 0, 0, 0);
    c = __builtin_amdgcn_mfma_f32_16x16x32_bf16(aq1, bk1[nt], c, 0, 0, 0);
    sc[nt] = c;
  }

  // 3-way mask: outside window -> -inf; zero-padded key -> score 0; else scale
#pragma unroll
  for (int nt = 0; nt < 8; nt++) {
#pragma unroll
    for (int r = 0; r < 4; r++) {
      int j = s0 - 32 + nt * 16 + lrow;        // key (col)
      int i = s0 + wave * 16 + quad * 4 + r;   // query (row)
      int w = j - i + 32;
      float s = sc[nt][r] * 0.125f;
      if (w < 0 || w > 63) s = -1e30f;
      else if (j < 0 || j >= SEQ) s = 0.0f;
      sc[nt][r] = s;
    }
  }

  // row softmax: in-register across 8 n-tiles, then 16-lane xor-reduce
  float linv[4];
#pragma unroll
  for (int r = 0; r < 4; r++) {
    float m = sc[0][r];
#pragma unroll
    for (int nt = 1; nt < 8; nt++) m = fmaxf(m, sc[nt][r]);
    m = fmaxf(m, __shfl_xor(m, 1, 64));
    m = fmaxf(m, __shfl_xor(m, 2, 64));
    m = fmaxf(m, __shfl_xor(m, 4, 64));
    m = fmaxf(m, __shfl_xor(m, 8, 64));
    float l = 0.f;
#pragma unroll
    for (int nt = 0; nt < 8; nt++) {
      float p = __expf(sc[nt][r] - m);
      sc[nt][r] = p;
      l += p;
    }
    l += __shfl_xor(l, 1, 64);
    l += __shfl_xor(l, 2, 64);
    l += __shfl_xor(l, 4, 64);
    l += __shfl_xor(l, 8, 64);
    linv[r] = 1.0f / l;  // never 0: diagonal key always contributes
  }

  // P (C-layout) -> LDS bf16 in row-major for A-operand reads (wave-private)
#pragma unroll
  for (int nt = 0; nt < 8; nt++)
#pragma unroll
    for (int r = 0; r < 4; r++)
      P[wave][quad * 4 + r][nt * 16 + lrow] = f2b(sc[nt][r]);

  // ctx = P~ * V  (A from P LDS, B from VT LDS), then normalize by 1/l
#pragma unroll
  for (int dt = 0; dt < 4; dt++) {
    f32x4 o = {0.f, 0.f, 0.f, 0.f};
#pragma unroll
    for (int kk = 0; kk < 4; kk++) {
      bf16x8 pa = *(const bf16x8*)&P[wave][lrow][kk * 32 + quad * 8];
      bf16x8 vb = *(const bf16x8*)&VT[dt * 16 + lrow][kk * 32 + quad * 8];
      o = __builtin_amdgcn_mfma_f32_16x16x32_bf16(pa, vb, o, 0, 0, 0);
    }
#pragma unroll
    for (int r = 0; r < 4; r++) {
      int token = b * SEQ + s0 + wave * 16 + quad * 4 + r;
      ctx[(size_t)token * H_SZ + h * 64 + dt * 16 + lrow] =
          f2b(o[r] * linv[r]);
    }
  }
}

extern "C" void kernel_launch(void* const* d_in, const int* in_sizes, int n_in,
                              void* d_out, int out_size, void* d_ws,
                              size_t ws_size, hipStream_t stream) {
  (void)in_sizes; (void)n_in; (void)out_size; (void)ws_size;
  const float* hs = (const float*)d_in[0];
  const float* Wq = (const float*)d_in[1];
  const float* bq = (const float*)d_in[2];
  const float* Wk = (const float*)d_in[3];
  const float* bk = (const float*)d_in[4];
  const float* Wv = (const float*)d_in[5];
  const float* bv = (const float*)d_in[6];
  const float* Wo = (const float*)d_in[7];
  const float* bo = (const float*)d_in[8];
  float* out = (float*)d_out;
  char* ws = (char*)d_ws;
  char* ob = (char*)d_out;
  // d_out-resident scratch (fully overwritten by final GEMM):
  u16* xb = (u16*)(ob + XB_OUT_OFF);  // bf16 X, dead after QKV GEMM
  u16* qw = (u16*)(ob + QW_OUT_OFF);  // Q planes, dead after attn
  // ws-resident scratch (10.5 MiB total):
  u16* wqkvb = (u16*)(ws + WQKV_OFF);
  u16* kw = (u16*)(ws + KW_OFF);
  u16* vw = (u16*)(ws + VW_OFF);
  u16* wob = (u16*)(ws + WO_OFF);
  u16* ctx = (u16*)(ws + CTX_OFF);  // aliases wqkvb (dead after QKV GEMM)

  prep_kernel<<<3840, 256, 0, stream>>>(hs, Wq, Wk, Wv, Wo, xb, wqkvb, wob);
  gemm_bt<0, 64, 128, 64><<<dim3(18, 32), 256, 0, stream>>>(
      xb, wqkvb, 768, bq, bk, bv, qw, kw, vw, nullptr);
  attn_kernel<<<dim3(24, 16), 256, 0, stream>>>(qw, kw, vw, ctx);
  gemm_bt<1, 64, 64, 64><<<dim3(12, 32), 256, 0, stream>>>(
      ctx, wob, 768, bo, nullptr, nullptr, nullptr, nullptr, nullptr, out);
}